// Round 6
// baseline (212.230 us; speedup 1.0000x reference)
//
#include <hip/hip_runtime.h>
#include <stdint.h>

// x [3,5,32,64,32,32] binary float -> per 32x32 image max(component size, bg count)
// -> sum over 64 patches >> 6 -> float [480].
//
// TWO images per wave: lanes 0-31 own image A's rows, lanes 32-63 image B's.
// Row-per-lane bitmasks (input exactly 0.0f/1.0f -> pixel = floatbits>>29).
// Runs numbered by segmented 64-lane scan. Edge phase: DIRECT-HOOK atomicCAS
// (a>b always) with full lock-free union fallback; path-halving finds.
// Count phase: parallel pointer-jumping over the lane's <=16 runs in an
// unrolled register array (independent pipelined LDS reads), then pipelined
// atomicAdds of run lengths into root entries (L[r] = r | size<<9).
// Wave-lockstep => no barriers.

#define N_IMGS 30720
#define N_OUT  480
#define WAVES_PER_BLOCK 4
#define IMGS_PER_BLOCK (WAVES_PER_BLOCK * 2)   // 8

__device__ __forceinline__ int findH(int* L, int i) {
    for (;;) {
        int p = L[i] & 511;
        if (p == i) return i;
        int g = L[p] & 511;
        if (g == p) return p;
        L[i] = g;          // halving: shortcut to grandparent (monotone-safe)
        i = g;
    }
}

__global__ __launch_bounds__(256)
void ccl_wave2_kernel(const uint32_t* __restrict__ x, int* __restrict__ maxc) {
    __shared__ int Lbuf[IMGS_PER_BLOCK * 512];   // 16 KiB

    const int lane = threadIdx.x & 63;
    const int wv   = threadIdx.x >> 6;
    const int half = lane >> 5;                  // 0: image A, 1: image B
    const int row  = lane & 31;
    const size_t img = (size_t)blockIdx.x * IMGS_PER_BLOCK + wv * 2 + half;
    int* L = Lbuf + (wv * 2 + half) * 512;

    // ---- row-per-lane load: 8 x uint4 = 32 pixels; 1.0f bits >>29 == 1 ----
    const uint4* rp = (const uint4*)(x + img * 1024 + row * 32);
    uint32_t m = 0;
    #pragma unroll
    for (int i = 0; i < 8; ++i) {
        uint4 q = rp[i];
        m |= (q.x >> 29) << (4 * i + 0);
        m |= (q.y >> 29) << (4 * i + 1);
        m |= (q.z >> 29) << (4 * i + 2);
        m |= (q.w >> 29) << (4 * i + 3);
    }

    // foreground count per image (butterfly within 32-lane half)
    int fg = __popc(m);
    #pragma unroll
    for (int off = 1; off < 32; off <<= 1) fg += __shfl_xor(fg, off);

    // ---- run numbering: 64-lane inclusive scan, segmented at lane 32 ----
    uint32_t runStarts = m & ~(m << 1);
    int nruns = __popc(runStarts);
    int scan = nruns;
    #pragma unroll
    for (int off = 1; off < 64; off <<= 1) {
        int u = __shfl_up(scan, off);
        if (lane >= off) scan += u;
    }
    const int totalA   = __shfl(scan, 31);
    const int totalAll = __shfl(scan, 63);
    const int base = scan - nruns - (half ? totalA : 0);
    const int R    = half ? (totalAll - totalA) : totalA;   // runs in my image

    for (int i = row; i < R; i += 32) L[i] = i;

    // ---- edges: one per overlap segment with previous row ----
    uint32_t mprev  = __shfl_up(m, 1);
    uint32_t rsPrev = __shfl_up(runStarts, 1);
    int      bPrev  = __shfl_up(base, 1);
    if (row == 0) mprev = 0;                 // row 0 of each image
    uint32_t ov  = m & mprev;
    uint32_t ovs = ov & ~(ov << 1);

    while (ovs) {
        int c = __ffs(ovs) - 1; ovs &= ovs - 1;
        uint32_t mc = (2u << c) - 1;         // bits 0..c (c=31 -> all ones)
        int a = base  + __popc(runStarts & mc) - 1;
        int b = bPrev + __popc(rsPrev    & mc) - 1;
        // direct hook: a was created this row (a > b). One LDS round-trip in
        // the common case; full lock-free union only if a is already hooked.
        int old = atomicCAS(&L[a], a, b);
        if (old != a) {
            int ra = findH(L, a);
            int rb = findH(L, b);
            while (ra != rb) {               // hook larger root to smaller
                int hi = ra > rb ? ra : rb;
                int lo = ra ^ rb ^ hi;
                int o2 = atomicCAS(&L[hi], hi, lo);
                if (o2 == hi) break;         // hooked
                ra = findH(L, o2 & 511);     // root moved; chase and retry
                rb = lo;
            }
        }
    }
    // wave reconverges here: all unions complete before any lane proceeds.

    // ---- parallel pointer-jumping: resolve roots of my row's <=16 runs ----
    // Register array, fully unrolled => stays in VGPRs; each level issues
    // independent LDS reads that pipeline instead of serializing.
    int rr[16];
    #pragma unroll
    for (int j = 0; j < 16; ++j) rr[j] = base + j;
    bool changed = true;
    while (changed) {
        changed = false;
        #pragma unroll
        for (int j = 0; j < 16; ++j) {
            if (j < nruns) {
                int p = L[rr[j]] & 511;
                if (p != rr[j]) { rr[j] = p; changed = true; }
            }
        }
    }

    // ---- sizes into roots: L[r] = r | (size<<9); adds never touch low 9b ----
    uint32_t mm = m;
    #pragma unroll
    for (int j = 0; j < 16; ++j) {
        if (j < nruns) {
            int s = __ffs(mm) - 1;
            uint32_t t  = mm + (1u << s);
            uint32_t rm = (t ^ mm) & mm;     // this run's bits
            mm &= ~rm;
            atomicAdd(&L[rr[j]], __popc(rm) << 9);
        }
    }

    // ---- max component size, per image ----
    int mx = 0;
    for (int i = row; i < R; i += 32) {
        int v = L[i];
        if ((v & 511) == i) mx = max(mx, v >> 9);
    }
    #pragma unroll
    for (int off = 1; off < 32; off <<= 1) mx = max(mx, __shfl_xor(mx, off));

    if (row == 0) maxc[img] = max(mx, 1024 - fg);
}

__global__ __launch_bounds__(64)
void patch_reduce_kernel(const int* __restrict__ maxc, float* __restrict__ out) {
    const int o = blockIdx.x;   // 0..479
    int v = maxc[(size_t)o * 64 + threadIdx.x];
    #pragma unroll
    for (int off = 32; off > 0; off >>= 1)
        v += __shfl_down(v, off);
    if (threadIdx.x == 0) out[o] = (float)(v >> 6);  // integer division by 64
}

extern "C" void kernel_launch(void* const* d_in, const int* in_sizes, int n_in,
                              void* d_out, int out_size, void* d_ws, size_t ws_size,
                              hipStream_t stream) {
    const uint32_t* x = (const uint32_t*)d_in[0];   // float bits; 1.0f>>29 == 1
    float* out = (float*)d_out;
    int* maxc = (int*)d_ws;   // 30720 ints

    ccl_wave2_kernel<<<N_IMGS / IMGS_PER_BLOCK, 256, 0, stream>>>(x, maxc);
    patch_reduce_kernel<<<N_OUT, 64, 0, stream>>>(maxc, out);
}

// Round 7
// 192.313 us; speedup vs baseline: 1.1036x; 1.1036x over previous
//
#include <hip/hip_runtime.h>
#include <stdint.h>

// x [3,5,32,64,32,32] binary float -> per 32x32 image max(component size, bg count)
// -> sum over 64 patches >> 6 -> float [480].
//
// TWO images per wave: lanes 0-31 own image A's rows, lanes 32-63 image B's.
// Row-per-lane bitmasks (input exactly 0.0f/1.0f -> pixel = floatbits>>29).
// Runs numbered by segmented 64-lane scan. Edge phase (R5-proven): lock-free
// union with atomicCAS hooking LARGER ROOT -> SMALLER ROOT, path-halving
// finds => trees stay shallow (depth <~3). Count phase: batched two-level
// parent resolve (independent pipelined LDS reads) + serial findH fallback,
// then pipelined atomicAdds of run lengths into roots (L[r] = r | size<<9).
// Wave-lockstep => no barriers.

#define N_IMGS 30720
#define N_OUT  480
#define WAVES_PER_BLOCK 4
#define IMGS_PER_BLOCK (WAVES_PER_BLOCK * 2)   // 8

// Find with path halving. child -> parent id (<512, strictly smaller);
// root r -> r | (size<<9) (size bits appear only in count phase; &511 strips).
__device__ __forceinline__ int findH(int* L, int i) {
    for (;;) {
        int p = L[i] & 511;
        if (p == i) return i;
        int g = L[p] & 511;
        if (g == p) return p;
        L[i] = g;          // halving: shortcut to grandparent (monotone-safe)
        i = g;
    }
}

__global__ __launch_bounds__(256)
void ccl_wave2_kernel(const uint32_t* __restrict__ x, int* __restrict__ maxc) {
    __shared__ int Lbuf[IMGS_PER_BLOCK * 512];   // 16 KiB

    const int lane = threadIdx.x & 63;
    const int wv   = threadIdx.x >> 6;
    const int half = lane >> 5;                  // 0: image A, 1: image B
    const int row  = lane & 31;
    const size_t img = (size_t)blockIdx.x * IMGS_PER_BLOCK + wv * 2 + half;
    int* L = Lbuf + (wv * 2 + half) * 512;

    // ---- row-per-lane load: 8 x uint4 = 32 pixels; 1.0f bits >>29 == 1 ----
    const uint4* rp = (const uint4*)(x + img * 1024 + row * 32);
    uint32_t m = 0;
    #pragma unroll
    for (int i = 0; i < 8; ++i) {
        uint4 q = rp[i];
        m |= (q.x >> 29) << (4 * i + 0);
        m |= (q.y >> 29) << (4 * i + 1);
        m |= (q.z >> 29) << (4 * i + 2);
        m |= (q.w >> 29) << (4 * i + 3);
    }

    // foreground count per image (butterfly within 32-lane half)
    int fg = __popc(m);
    #pragma unroll
    for (int off = 1; off < 32; off <<= 1) fg += __shfl_xor(fg, off);

    // ---- run numbering: 64-lane inclusive scan, segmented at lane 32 ----
    uint32_t runStarts = m & ~(m << 1);
    int nruns = __popc(runStarts);
    int scan = nruns;
    #pragma unroll
    for (int off = 1; off < 64; off <<= 1) {
        int u = __shfl_up(scan, off);
        if (lane >= off) scan += u;
    }
    const int totalA   = __shfl(scan, 31);
    const int totalAll = __shfl(scan, 63);
    const int base = scan - nruns - (half ? totalA : 0);
    const int R    = half ? (totalAll - totalA) : totalA;   // runs in my image

    // conflict-free init: lane r writes indices r, r+32, ... (distinct banks)
    for (int i = row; i < R; i += 32) L[i] = i;

    // ---- edges: one per overlap segment with previous row ----
    uint32_t mprev  = __shfl_up(m, 1);
    uint32_t rsPrev = __shfl_up(runStarts, 1);
    int      bPrev  = __shfl_up(base, 1);
    if (row == 0) mprev = 0;                 // row 0 of each image
    uint32_t ov  = m & mprev;
    uint32_t ovs = ov & ~(ov << 1);

    while (ovs) {
        int c = __ffs(ovs) - 1; ovs &= ovs - 1;
        uint32_t mc = (2u << c) - 1;         // bits 0..c (c=31 -> all ones)
        int a = base  + __popc(runStarts & mc) - 1;
        int b = bPrev + __popc(rsPrev    & mc) - 1;
        int ra = findH(L, a);
        int rb = findH(L, b);
        while (ra != rb) {                   // hook larger ROOT to smaller
            int hi = ra > rb ? ra : rb;
            int lo = ra ^ rb ^ hi;
            int old = atomicCAS(&L[hi], hi, lo);
            if (old == hi) break;            // hooked
            ra = findH(L, old & 511);        // root moved; chase and retry
            rb = lo;
        }
    }
    // wave reconverges here: all unions complete before any lane proceeds.

    // ---- count phase: batched two-level resolve (pipelined), then fallback.
    // Trees are shallow (root-to-root hooking + halving), so two independent
    // read waves resolve almost all runs; findH handles stragglers.
    int rr[16];
    #pragma unroll
    for (int j = 0; j < 16; ++j) {
        if (j < nruns) rr[j] = L[base + j] & 511;       // level 1 (independent)
    }
    #pragma unroll
    for (int j = 0; j < 16; ++j) {
        if (j < nruns) rr[j] = L[rr[j]] & 511;          // level 2 (independent)
    }
    #pragma unroll
    for (int j = 0; j < 16; ++j) {
        if (j < nruns) {
            int p = L[rr[j]] & 511;
            if (p != rr[j]) rr[j] = findH(L, p);        // rare deep fallback
        }
    }

    // ---- sizes into roots: L[r] = r | (size<<9); adds never touch low 9b ----
    uint32_t mm = m;
    #pragma unroll
    for (int j = 0; j < 16; ++j) {
        if (j < nruns) {
            int s = __ffs(mm) - 1;
            uint32_t t  = mm + (1u << s);
            uint32_t rm = (t ^ mm) & mm;     // this run's bits
            mm &= ~rm;
            atomicAdd(&L[rr[j]], __popc(rm) << 9);
        }
    }

    // ---- max component size, per image (conflict-free strided scan) ----
    int mx = 0;
    for (int i = row; i < R; i += 32) {
        int v = L[i];
        if ((v & 511) == i) mx = max(mx, v >> 9);
    }
    #pragma unroll
    for (int off = 1; off < 32; off <<= 1) mx = max(mx, __shfl_xor(mx, off));

    if (row == 0) maxc[img] = max(mx, 1024 - fg);
}

__global__ __launch_bounds__(64)
void patch_reduce_kernel(const int* __restrict__ maxc, float* __restrict__ out) {
    const int o = blockIdx.x;   // 0..479
    int v = maxc[(size_t)o * 64 + threadIdx.x];
    #pragma unroll
    for (int off = 32; off > 0; off >>= 1)
        v += __shfl_down(v, off);
    if (threadIdx.x == 0) out[o] = (float)(v >> 6);  // integer division by 64
}

extern "C" void kernel_launch(void* const* d_in, const int* in_sizes, int n_in,
                              void* d_out, int out_size, void* d_ws, size_t ws_size,
                              hipStream_t stream) {
    const uint32_t* x = (const uint32_t*)d_in[0];   // float bits; 1.0f>>29 == 1
    float* out = (float*)d_out;
    int* maxc = (int*)d_ws;   // 30720 ints

    ccl_wave2_kernel<<<N_IMGS / IMGS_PER_BLOCK, 256, 0, stream>>>(x, maxc);
    patch_reduce_kernel<<<N_OUT, 64, 0, stream>>>(maxc, out);
}

// Round 8
// 191.340 us; speedup vs baseline: 1.1092x; 1.0051x over previous
//
#include <hip/hip_runtime.h>
#include <stdint.h>

// x [3,5,32,64,32,32] binary float -> per 32x32 image max(component size, bg count)
// -> sum over 64 patches >> 6 -> float [480].
//
// TWO images per wave: lanes 0-31 own image A's rows, lanes 32-63 image B's.
// Row-per-lane bitmasks (input exactly 0.0f/1.0f -> pixel = floatbits>>29).
// Runs numbered by segmented 64-lane scan. Edge phase: lock-free union with
// atomicCAS hooking LARGER ROOT -> SMALLER ROOT; JOINT dual-chain find with
// path halving (parent+grandparent reads for both endpoints issued together,
// pipelined in the LDS queue) + current-run root cache. Count phase: batched
// two-level parent resolve + serial fallback, then pipelined atomicAdds of
// run lengths into roots (L[r] = r | size<<9). Wave-lockstep => no barriers.

#define N_IMGS 30720
#define N_OUT  480
#define WAVES_PER_BLOCK 4
#define IMGS_PER_BLOCK (WAVES_PER_BLOCK * 2)   // 8

// Serial find with path halving (used only on rare CAS-retry / deep paths).
__device__ __forceinline__ int findH(int* L, int i) {
    for (;;) {
        int p = L[i] & 511;
        if (p == i) return i;
        int g = L[p] & 511;
        if (g == p) return p;
        L[i] = g;          // halving: shortcut to grandparent (monotone-safe)
        i = g;
    }
}

__global__ __launch_bounds__(256)
void ccl_wave2_kernel(const uint32_t* __restrict__ x, int* __restrict__ maxc) {
    __shared__ int Lbuf[IMGS_PER_BLOCK * 512];   // 16 KiB

    const int lane = threadIdx.x & 63;
    const int wv   = threadIdx.x >> 6;
    const int half = lane >> 5;                  // 0: image A, 1: image B
    const int row  = lane & 31;
    const size_t img = (size_t)blockIdx.x * IMGS_PER_BLOCK + wv * 2 + half;
    int* L = Lbuf + (wv * 2 + half) * 512;

    // ---- row-per-lane load: 8 x uint4 = 32 pixels; 1.0f bits >>29 == 1 ----
    const uint4* rp = (const uint4*)(x + img * 1024 + row * 32);
    uint32_t m = 0;
    #pragma unroll
    for (int i = 0; i < 8; ++i) {
        uint4 q = rp[i];
        m |= (q.x >> 29) << (4 * i + 0);
        m |= (q.y >> 29) << (4 * i + 1);
        m |= (q.z >> 29) << (4 * i + 2);
        m |= (q.w >> 29) << (4 * i + 3);
    }

    // foreground count per image (butterfly within 32-lane half)
    int fg = __popc(m);
    #pragma unroll
    for (int off = 1; off < 32; off <<= 1) fg += __shfl_xor(fg, off);

    // ---- run numbering: 64-lane inclusive scan, segmented at lane 32 ----
    uint32_t runStarts = m & ~(m << 1);
    int nruns = __popc(runStarts);
    int scan = nruns;
    #pragma unroll
    for (int off = 1; off < 64; off <<= 1) {
        int u = __shfl_up(scan, off);
        if (lane >= off) scan += u;
    }
    const int totalA   = __shfl(scan, 31);
    const int totalAll = __shfl(scan, 63);
    const int base = scan - nruns - (half ? totalA : 0);
    const int R    = half ? (totalAll - totalA) : totalA;   // runs in my image

    for (int i = row; i < R; i += 32) L[i] = i;

    // ---- edges: one per overlap segment with previous row ----
    uint32_t mprev  = __shfl_up(m, 1);
    uint32_t rsPrev = __shfl_up(runStarts, 1);
    int      bPrev  = __shfl_up(base, 1);
    if (row == 0) mprev = 0;                 // row 0 of each image
    uint32_t ov  = m & mprev;
    uint32_t ovs = ov & ~(ov << 1);

    int lastA = -1, rootA = -1;              // cache: root of current-row run
    while (ovs) {
        int c = __ffs(ovs) - 1; ovs &= ovs - 1;
        uint32_t mc = (2u << c) - 1;         // bits 0..c (c=31 -> all ones)
        int a = base  + __popc(runStarts & mc) - 1;
        int b = bPrev + __popc(rsPrev    & mc) - 1;

        int ra = (a == lastA) ? rootA : a;   // reuse merged root if same run
        int rb = b;
        // joint dual-chain find: both chains advance 2 levels per iteration;
        // the 4 LDS reads are independent and pipeline in the queue.
        for (;;) {
            int pa = L[ra] & 511;
            int pb = L[rb] & 511;
            if (pa == ra && pb == rb) break;
            int ga = L[pa] & 511;            // grandparents (independent)
            int gb = L[pb] & 511;
            if (pa != ra) { L[ra] = ga; ra = ga; }
            if (pb != rb) { L[rb] = gb; rb = gb; }
        }
        while (ra != rb) {                   // hook larger ROOT to smaller
            int hi = ra > rb ? ra : rb;
            int lo = ra ^ rb ^ hi;
            int old = atomicCAS(&L[hi], hi, lo);
            if (old == hi) { ra = lo; break; }   // hooked; merged root = lo
            ra = findH(L, old & 511);        // root moved; chase and retry
            rb = lo;
        }
        lastA = a; rootA = ra;
    }
    // wave reconverges here: all unions complete before any lane proceeds.

    // ---- count phase: batched two-level resolve (pipelined), then fallback.
    int rr[16];
    #pragma unroll
    for (int j = 0; j < 16; ++j) {
        if (j < nruns) rr[j] = L[base + j] & 511;       // level 1 (independent)
    }
    #pragma unroll
    for (int j = 0; j < 16; ++j) {
        if (j < nruns) rr[j] = L[rr[j]] & 511;          // level 2 (independent)
    }
    #pragma unroll
    for (int j = 0; j < 16; ++j) {
        if (j < nruns) {
            int p = L[rr[j]] & 511;
            if (p != rr[j]) rr[j] = findH(L, p);        // rare deep fallback
        }
    }

    // ---- sizes into roots: L[r] = r | (size<<9); adds never touch low 9b ----
    uint32_t mm = m;
    #pragma unroll
    for (int j = 0; j < 16; ++j) {
        if (j < nruns) {
            int s = __ffs(mm) - 1;
            uint32_t t  = mm + (1u << s);
            uint32_t rm = (t ^ mm) & mm;     // this run's bits
            mm &= ~rm;
            atomicAdd(&L[rr[j]], __popc(rm) << 9);
        }
    }

    // ---- max component size, per image (strided, conflict-free) ----
    int mx = 0;
    for (int i = row; i < R; i += 32) {
        int v = L[i];
        if ((v & 511) == i) mx = max(mx, v >> 9);
    }
    #pragma unroll
    for (int off = 1; off < 32; off <<= 1) mx = max(mx, __shfl_xor(mx, off));

    if (row == 0) maxc[img] = max(mx, 1024 - fg);
}

__global__ __launch_bounds__(64)
void patch_reduce_kernel(const int* __restrict__ maxc, float* __restrict__ out) {
    const int o = blockIdx.x;   // 0..479
    int v = maxc[(size_t)o * 64 + threadIdx.x];
    #pragma unroll
    for (int off = 32; off > 0; off >>= 1)
        v += __shfl_down(v, off);
    if (threadIdx.x == 0) out[o] = (float)(v >> 6);  // integer division by 64
}

extern "C" void kernel_launch(void* const* d_in, const int* in_sizes, int n_in,
                              void* d_out, int out_size, void* d_ws, size_t ws_size,
                              hipStream_t stream) {
    const uint32_t* x = (const uint32_t*)d_in[0];   // float bits; 1.0f>>29 == 1
    float* out = (float*)d_out;
    int* maxc = (int*)d_ws;   // 30720 ints

    ccl_wave2_kernel<<<N_IMGS / IMGS_PER_BLOCK, 256, 0, stream>>>(x, maxc);
    patch_reduce_kernel<<<N_OUT, 64, 0, stream>>>(maxc, out);
}